// Round 9
// baseline (3973.354 us; speedup 1.0000x reference)
//
#include <hip/hip_runtime.h>
#include <hip/hip_bf16.h>

#define M_DIM 8192
#define N_DIM 11008
#define K_DIM 4096
#define NT 32                        // K-tiles of BK=128 (int8)
#define RROW ((size_t)64 * K_DIM)    // 64 rows of int8, in bytes

typedef __attribute__((ext_vector_type(4))) int i32x4;

// ---------------- per-token activation quant: n = rint(x/s), s = max(absmax,1e-5)/7 ----------------
__global__ void quant_x_kernel(const float* __restrict__ x,
                               char* __restrict__ xq, float* __restrict__ sx) {
  const int row = blockIdx.x;      // 8192
  const int t = threadIdx.x;       // 256
  const float4* xr4 = (const float4*)(x + (size_t)row * K_DIM);
  float4 v[4];
  float amax = 0.0f;
#pragma unroll
  for (int i = 0; i < 4; ++i) {
    v[i] = xr4[t + 256 * i];
    amax = fmaxf(amax, fmaxf(fmaxf(fabsf(v[i].x), fabsf(v[i].y)),
                             fmaxf(fabsf(v[i].z), fabsf(v[i].w))));
  }
#pragma unroll
  for (int off = 32; off > 0; off >>= 1)
    amax = fmaxf(amax, __shfl_xor(amax, off, 64));
  __shared__ float red[4];
  if ((t & 63) == 0) red[t >> 6] = amax;
  __syncthreads();
  amax = fmaxf(fmaxf(red[0], red[1]), fmaxf(red[2], red[3]));
  const float s = fmaxf(amax, 1e-5f) / 7.0f;   // matches reference bitwise
  if (t == 0) sx[row] = s;
  char q[16];
#pragma unroll
  for (int i = 0; i < 4; ++i) {
    q[i * 4 + 0] = (char)(int)rintf(v[i].x / s);  // RNE, exact ints in [-7,7]
    q[i * 4 + 1] = (char)(int)rintf(v[i].y / s);
    q[i * 4 + 2] = (char)(int)rintf(v[i].z / s);
    q[i * 4 + 3] = (char)(int)rintf(v[i].w / s);
  }
  *(int4*)(xq + (size_t)row * K_DIM + t * 16) = *(int4*)q;
}

// ---------------- per-output-channel weight quant: int8/127, PACKED frag-linear ----------------
// Pack: W[n][c..c+15] -> wqp[(((n>>6)*4 + ((n>>4)&3))*64 + (c>>6))*64 + ((c>>4)&3)*16 + (n&15)]*16
// so a wave's B-fragment (f, kstep) is ONE contiguous 1 KB block (lane-linear).
__global__ void quant_w_kernel(const float* __restrict__ w,
                               char* __restrict__ wqp, float* __restrict__ sw) {
  const int row = blockIdx.x;      // 11008
  const int t = threadIdx.x;       // 256
  const float4* wr4 = (const float4*)(w + (size_t)row * K_DIM);
  float4 v[4];
  float amax = 0.0f;
#pragma unroll
  for (int i = 0; i < 4; ++i) {
    v[i] = wr4[t + 256 * i];
    amax = fmaxf(amax, fmaxf(fmaxf(fabsf(v[i].x), fabsf(v[i].y)),
                             fmaxf(fabsf(v[i].z), fabsf(v[i].w))));
  }
#pragma unroll
  for (int off = 32; off > 0; off >>= 1)
    amax = fmaxf(amax, __shfl_xor(amax, off, 64));
  __shared__ float red[4];
  if ((t & 63) == 0) red[t >> 6] = amax;
  __syncthreads();
  amax = fmaxf(fmaxf(red[0], red[1]), fmaxf(red[2], red[3]));
  const float s = fmaxf(amax, 1e-30f) / 127.0f;
  if (t == 0) sw[row] = s;
  char q[16];
#pragma unroll
  for (int i = 0; i < 4; ++i) {
    q[i * 4 + 0] = (char)(int)rintf(v[i].x / s);  // in [-127,127]
    q[i * 4 + 1] = (char)(int)rintf(v[i].y / s);
    q[i * 4 + 2] = (char)(int)rintf(v[i].z / s);
    q[i * 4 + 3] = (char)(int)rintf(v[i].w / s);
  }
  const int g64 = row >> 6, f = (row >> 4) & 3, lr = row & 15;
  const int ks = t >> 2, hi = t & 3;
  const size_t idx16 = (((size_t)g64 * 4 + f) * 64 + ks) * 64 + hi * 16 + lr;
  *(int4*)(wqp + idx16 * 16) = *(int4*)q;
}

// ---------------- GEMM ----------------
// 256x256 tile, BK=128 int8, 512 thr (8 waves 2x4). A-only LDS (64 KiB dbuf,
// XOR-swizzled, 0 conflicts) -> 2 blocks/CU co-resident; their barriers are
// unsynchronized, so the other block's waves cover read phases / barrier drains
// (m114 cross-block overlap). B: fragment-packed W, contiguous 1KB coalesced
// loads issued one full tile ahead (double reg bank), L2-hot via bm-fastest
// XCD swizzle. LDS/tile = 160 KB < MFMA floor 2609 cyc.
#define GL(g, d)                                                             \
  __builtin_amdgcn_global_load_lds(                                          \
      (const __attribute__((address_space(1))) void*)(g),                    \
      (__attribute__((address_space(3))) void*)(d), 16, 0, 0)

#define MFMA_I8 __builtin_amdgcn_mfma_i32_16x16x64_i8

template<bool STG, bool LB>
__device__ __forceinline__ void tile_body(const char* pa, int colswz,
    const char* gAn, char* dA, const char* gBnxt,
    i32x4 (&bc)[8], i32x4 (&bn)[8], i32x4 (&acc)[8][4]) {
  __syncthreads();   // A(t) staged & B(t) landed; prev-buffer readers done
  if constexpr (STG) {  // stage A(t+1)
    GL(gAn, dA);                    GL(gAn + RROW, dA + 8192);
    GL(gAn + 2 * RROW, dA + 16384); GL(gAn + 3 * RROW, dA + 24576);
  }
  if constexpr (LB) {   // load B(t+1): 8 contiguous 1KB fragments
#pragma unroll
    for (int f = 0; f < 4; ++f) {
      bn[f]     = *(const i32x4*)(gBnxt + (size_t)f * 65536);
      bn[4 + f] = *(const i32x4*)(gBnxt + (size_t)f * 65536 + 1024);
    }
  }
  i32x4 a[8];
  // k0
#pragma unroll
  for (int f = 0; f < 8; ++f)
    a[f] = *(const i32x4*)(pa + f * 2048 + colswz);
#pragma unroll
  for (int m = 0; m < 8; ++m)
#pragma unroll
    for (int n = 0; n < 4; ++n)
      acc[m][n] = MFMA_I8(a[m], bc[n], acc[m][n], 0, 0, 0);
  // k1
#pragma unroll
  for (int f = 0; f < 8; ++f)
    a[f] = *(const i32x4*)(pa + f * 2048 + (colswz ^ 64));
#pragma unroll
  for (int m = 0; m < 8; ++m)
#pragma unroll
    for (int n = 0; n < 4; ++n)
      acc[m][n] = MFMA_I8(a[m], bc[4 + n], acc[m][n], 0, 0, 0);
}

__global__ __launch_bounds__(512, 4) void gemm_kernel(
    const char* __restrict__ xq, const char* __restrict__ wqp,
    const float* __restrict__ sx, const float* __restrict__ sw,
    const float* __restrict__ bias, float* __restrict__ out) {
  __shared__ char lds_c[65536];  // A only: bufs 0/1 of 32 KiB

  const int tid = threadIdx.x;
  const int lane = tid & 63;
  const int wave = tid >> 6;
  const int wm = wave >> 2;       // 0..1
  const int wn = wave & 3;        // 0..3
  const int lr = lane & 15;

  // bm-fastest bijective XCD swizzle (1376 = 8*172): the 32 co-resident blocks
  // of an XCD share one 1 MB B-panel in its L2 (validated R8: FETCH flat).
  const int bid = blockIdx.x;
  const int sw_id = (bid & 7) * 172 + (bid >> 3);
  const int bm = sw_id & 31, bn = sw_id >> 5;
  const int m0 = bm * 256, n0 = bn * 256;

  // A staging source (inverse swizzle, rule #21)
  const int srow = tid >> 3;
  const int srccb = ((tid & 7) << 4) ^ ((srow & 7) << 4);
  const char* gA0 = xq + (size_t)(m0 + srow) * K_DIM + srccb;
  char* dA0 = lds_c + wave * 1024;            // wave-uniform; HW adds lane*16

  // A read base (swizzled)
  const int aRowOff = (wm * 128 + lr) * 128;
  const int colswz = ((lane >> 4) << 4) ^ ((lr & 7) << 4);

  // B packed base for this wave: g64 = n0/64 + wn; frag f at +f*64KB, kstep at +ks*1KB
  const char* gB0 = wqp + ((size_t)((n0 >> 6) + wn)) * 262144 + lane * 16;

  i32x4 acc[8][4] = {};
  i32x4 b0[8], b1[8];

  // prologue: stage A(0) into buf 0; load B(0) into bank0
  GL(gA0, dA0);                    GL(gA0 + RROW, dA0 + 8192);
  GL(gA0 + 2 * RROW, dA0 + 16384); GL(gA0 + 3 * RROW, dA0 + 24576);
#pragma unroll
  for (int f = 0; f < 4; ++f) {
    b0[f]     = *(const i32x4*)(gB0 + (size_t)f * 65536);
    b0[4 + f] = *(const i32x4*)(gB0 + (size_t)f * 65536 + 1024);
  }

  for (int t = 0; t < NT - 2; t += 2) {
    tile_body<true, true>(lds_c + (t & 1) * 32768 + aRowOff, colswz,
                          gA0 + (size_t)(t + 1) * 128, dA0 + ((t + 1) & 1) * 32768,
                          gB0 + (size_t)(t + 1) * 2048, b0, b1, acc);
    tile_body<true, true>(lds_c + ((t + 1) & 1) * 32768 + aRowOff, colswz,
                          gA0 + (size_t)(t + 2) * 128, dA0 + ((t + 2) & 1) * 32768,
                          gB0 + (size_t)(t + 2) * 2048, b1, b0, acc);
  }
  // tile 30: stage A(31), load B(31); tile 31: nothing new
  tile_body<true, true>(lds_c + ((NT - 2) & 1) * 32768 + aRowOff, colswz,
                        gA0 + (size_t)(NT - 1) * 128, dA0 + ((NT - 1) & 1) * 32768,
                        gB0 + (size_t)(NT - 1) * 2048, b0, b1, acc);
  tile_body<false, false>(lds_c + ((NT - 1) & 1) * 32768 + aRowOff, colswz,
                          nullptr, nullptr, nullptr, b1, b0, acc);

  // epilogue: C/D layout col=lane&15, row=(lane>>4)*4+reg (dtype-independent, m121/m128)
  const int orow0 = m0 + wm * 128 + (lane >> 4) * 4;
  const int ocol0 = n0 + wn * 64 + lr;
  float bv[4], swv[4];
#pragma unroll
  for (int fc = 0; fc < 4; ++fc) {
    bv[fc] = bias[ocol0 + fc * 16];
    swv[fc] = sw[ocol0 + fc * 16];
  }
#pragma unroll
  for (int fr = 0; fr < 8; ++fr) {
#pragma unroll
    for (int j = 0; j < 4; ++j) {
      const int grow = orow0 + fr * 16 + j;
      const float s = sx[grow];
      float* op = out + (size_t)grow * N_DIM + ocol0;
#pragma unroll
      for (int fc = 0; fc < 4; ++fc)
        op[fc * 16] = (float)acc[fr][fc][j] * (s * swv[fc]) + bv[fc];
    }
  }
}

extern "C" void kernel_launch(void* const* d_in, const int* in_sizes, int n_in,
                              void* d_out, int out_size, void* d_ws, size_t ws_size,
                              hipStream_t stream) {
  (void)in_sizes; (void)n_in; (void)out_size; (void)ws_size;
  const float* x = (const float*)d_in[0];       // [4,2048,4096] f32
  const float* w = (const float*)d_in[1];       // [11008,4096] f32
  const float* bias = (const float*)d_in[2];    // [1,11008] f32
  float* out = (float*)d_out;                   // [8192,11008] f32

  char* ws = (char*)d_ws;
  float* sx = (float*)ws;                                   // 32 KiB
  float* sw = (float*)(ws + 32768);                         // 44 KiB
  char* xq8 = ws + 131072;                                  // 32 MiB int8
  char* wqp = ws + 131072 + (size_t)M_DIM * K_DIM;          // 43 MiB int8 (packed)

  quant_x_kernel<<<M_DIM, 256, 0, stream>>>(x, xq8, sx);
  quant_w_kernel<<<N_DIM, 256, 0, stream>>>(w, wqp, sw);
  gemm_kernel<<<dim3((M_DIM / 256) * (N_DIM / 256)), 512, 0, stream>>>(xq8, wqp, sx, sw, bias, out);
}

// Round 10
// 555.172 us; speedup vs baseline: 7.1570x; 7.1570x over previous
//
#include <hip/hip_runtime.h>
#include <hip/hip_bf16.h>

#define M_DIM 8192
#define N_DIM 11008
#define K_DIM 4096
#define NT 32                        // K-tiles of BK=128 (int8)
#define RROW ((size_t)64 * K_DIM)    // 64 rows of int8, in bytes

typedef __attribute__((ext_vector_type(4))) int i32x4;

// ---------------- per-token activation quant: n = rint(x/s), s = max(absmax,1e-5)/7 ----------------
__global__ void quant_x_kernel(const float* __restrict__ x,
                               char* __restrict__ xq, float* __restrict__ sx) {
  const int row = blockIdx.x;      // 8192
  const int t = threadIdx.x;       // 256
  const float4* xr4 = (const float4*)(x + (size_t)row * K_DIM);
  float4 v[4];
  float amax = 0.0f;
#pragma unroll
  for (int i = 0; i < 4; ++i) {
    v[i] = xr4[t + 256 * i];
    amax = fmaxf(amax, fmaxf(fmaxf(fabsf(v[i].x), fabsf(v[i].y)),
                             fmaxf(fabsf(v[i].z), fabsf(v[i].w))));
  }
#pragma unroll
  for (int off = 32; off > 0; off >>= 1)
    amax = fmaxf(amax, __shfl_xor(amax, off, 64));
  __shared__ float red[4];
  if ((t & 63) == 0) red[t >> 6] = amax;
  __syncthreads();
  amax = fmaxf(fmaxf(red[0], red[1]), fmaxf(red[2], red[3]));
  const float s = fmaxf(amax, 1e-5f) / 7.0f;   // matches reference bitwise
  if (t == 0) sx[row] = s;
  char q[16];
#pragma unroll
  for (int i = 0; i < 4; ++i) {
    q[i * 4 + 0] = (char)(int)rintf(v[i].x / s);  // RNE, exact ints in [-7,7]
    q[i * 4 + 1] = (char)(int)rintf(v[i].y / s);
    q[i * 4 + 2] = (char)(int)rintf(v[i].z / s);
    q[i * 4 + 3] = (char)(int)rintf(v[i].w / s);
  }
  *(int4*)(xq + (size_t)row * K_DIM + t * 16) = *(int4*)q;
}

// ---------------- per-output-channel weight quant: int8/127, PACKED frag-linear ----------------
// Pack verified R9 (absmax unchanged): W[n][c..c+15] ->
// wqp[((((n>>6)*4 + ((n>>4)&3))*64 + (c>>6))*64 + ((c>>4)&3)*16 + (n&15))*16]
// so a wave's B-fragment (f, kstep) is ONE contiguous 1 KB lane-linear block.
__global__ void quant_w_kernel(const float* __restrict__ w,
                               char* __restrict__ wqp, float* __restrict__ sw) {
  const int row = blockIdx.x;      // 11008
  const int t = threadIdx.x;       // 256
  const float4* wr4 = (const float4*)(w + (size_t)row * K_DIM);
  float4 v[4];
  float amax = 0.0f;
#pragma unroll
  for (int i = 0; i < 4; ++i) {
    v[i] = wr4[t + 256 * i];
    amax = fmaxf(amax, fmaxf(fmaxf(fabsf(v[i].x), fabsf(v[i].y)),
                             fmaxf(fabsf(v[i].z), fabsf(v[i].w))));
  }
#pragma unroll
  for (int off = 32; off > 0; off >>= 1)
    amax = fmaxf(amax, __shfl_xor(amax, off, 64));
  __shared__ float red[4];
  if ((t & 63) == 0) red[t >> 6] = amax;
  __syncthreads();
  amax = fmaxf(fmaxf(red[0], red[1]), fmaxf(red[2], red[3]));
  const float s = fmaxf(amax, 1e-30f) / 127.0f;
  if (t == 0) sw[row] = s;
  char q[16];
#pragma unroll
  for (int i = 0; i < 4; ++i) {
    q[i * 4 + 0] = (char)(int)rintf(v[i].x / s);  // in [-127,127]
    q[i * 4 + 1] = (char)(int)rintf(v[i].y / s);
    q[i * 4 + 2] = (char)(int)rintf(v[i].z / s);
    q[i * 4 + 3] = (char)(int)rintf(v[i].w / s);
  }
  const int g64 = row >> 6, f = (row >> 4) & 3, lr = row & 15;
  const int ks = t >> 2, hi = t & 3;
  const size_t idx16 = (((size_t)g64 * 4 + f) * 64 + ks) * 64 + hi * 16 + lr;
  *(int4*)(wqp + idx16 * 16) = *(int4*)q;
}

// ---------------- GEMM ----------------
// 256x256 tile, BK=128 int8, 512 thr (8 waves 2x4), __launch_bounds__(512,2)
// (R9's (512,4) reg-capped to 128 and spilled -> 4 ms; FIXED).
// A-only LDS (64 KiB dbuf, XOR-swizzled, 0 conflicts). B: frag-packed W,
// contiguous 1KB coalesced loads, L2-hot (bm-fastest XCD swizzle), triple-bank
// rotation: bk0 loaded one tile ahead; bk1(B t,k1)+bnx(B t+1,k0) at tile start
// (>=1400 cyc slack). LDS/tile 160 KB < MFMA 2611 cyc; segments pair each
// A-read cluster with an MFMA cluster so the LDS pipe hides under matrix pipe.
#define GL(g, d)                                                             \
  __builtin_amdgcn_global_load_lds(                                          \
      (const __attribute__((address_space(1))) void*)(g),                    \
      (__attribute__((address_space(3))) void*)(d), 16, 0, 0)

#define MFMA_I8 __builtin_amdgcn_mfma_i32_16x16x64_i8

template<bool STG, bool LBN>
__device__ __forceinline__ void tile_body(const char* pa, int colswz,
    const char* gAn, char* dA, const char* gBt1, const char* gBnx,
    i32x4 (&bk0)[4], i32x4 (&bk1)[4], i32x4 (&bnx)[4], i32x4 (&acc)[8][4]) {
  __syncthreads();   // A(t) staged; prev-buffer readers done
  if constexpr (STG) {  // stage A(t+1)
    GL(gAn, dA);                    GL(gAn + RROW, dA + 8192);
    GL(gAn + 2 * RROW, dA + 16384); GL(gAn + 3 * RROW, dA + 24576);
  }
  // B(t,k1) and B(t+1,k0): 1KB coalesced, consumed >=1 MFMA cluster later
#pragma unroll
  for (int f = 0; f < 4; ++f) bk1[f] = *(const i32x4*)(gBt1 + (size_t)f * 65536);
  if constexpr (LBN) {
#pragma unroll
    for (int f = 0; f < 4; ++f) bnx[f] = *(const i32x4*)(gBnx + (size_t)f * 65536);
  }
  i32x4 a[8], a2[4];
  // seg1: A k0 reads
#pragma unroll
  for (int f = 0; f < 8; ++f) a[f] = *(const i32x4*)(pa + f * 2048 + colswz);
  __builtin_amdgcn_sched_barrier(0);
  // seg2: A k1 reads (m0..3) || MFMA k0 (all m)
#pragma unroll
  for (int f = 0; f < 4; ++f) a2[f] = *(const i32x4*)(pa + f * 2048 + (colswz ^ 64));
#pragma unroll
  for (int m = 0; m < 8; ++m)
#pragma unroll
    for (int n = 0; n < 4; ++n)
      acc[m][n] = MFMA_I8(a[m], bk0[n], acc[m][n], 0, 0, 0);
  __builtin_amdgcn_sched_barrier(0);
  // seg3: A k1 reads (m4..7, reusing a[0..3]) || MFMA k1 (m0..3)
#pragma unroll
  for (int f = 0; f < 4; ++f) a[f] = *(const i32x4*)(pa + (4 + f) * 2048 + (colswz ^ 64));
#pragma unroll
  for (int m = 0; m < 4; ++m)
#pragma unroll
    for (int n = 0; n < 4; ++n)
      acc[m][n] = MFMA_I8(a2[m], bk1[n], acc[m][n], 0, 0, 0);
  __builtin_amdgcn_sched_barrier(0);
  // seg4: MFMA k1 (m4..7); rotate B banks
#pragma unroll
  for (int m = 0; m < 4; ++m)
#pragma unroll
    for (int n = 0; n < 4; ++n)
      acc[4 + m][n] = MFMA_I8(a[m], bk1[n], acc[4 + m][n], 0, 0, 0);
  if constexpr (LBN) {
#pragma unroll
    for (int f = 0; f < 4; ++f) bk0[f] = bnx[f];
  }
}

__global__ __launch_bounds__(512, 2) void gemm_kernel(
    const char* __restrict__ xq, const char* __restrict__ wqp,
    const float* __restrict__ sx, const float* __restrict__ sw,
    const float* __restrict__ bias, float* __restrict__ out) {
  __shared__ char lds_c[65536];  // A only: bufs 0/1 of 32 KiB

  const int tid = threadIdx.x;
  const int lane = tid & 63;
  const int wave = tid >> 6;
  const int wm = wave >> 2;       // 0..1
  const int wn = wave & 3;        // 0..3
  const int lr = lane & 15;

  // bm-fastest bijective XCD swizzle (1376 = 8*172): 32 co-resident blocks of
  // an XCD share one ~1 MB B-panel in its L2 (validated R8: FETCH flat).
  const int bid = blockIdx.x;
  const int sw_id = (bid & 7) * 172 + (bid >> 3);
  const int bm = sw_id & 31, bn = sw_id >> 5;
  const int m0 = bm * 256, n0 = bn * 256;

  // A staging source (inverse swizzle, rule #21)
  const int srow = tid >> 3;
  const int srccb = ((tid & 7) << 4) ^ ((srow & 7) << 4);
  const char* gA0 = xq + (size_t)(m0 + srow) * K_DIM + srccb;
  char* dA0 = lds_c + wave * 1024;            // wave-uniform; HW adds lane*16

  // A read base (swizzled)
  const int aRowOff = (wm * 128 + lr) * 128;
  const int colswz = ((lane >> 4) << 4) ^ ((lr & 7) << 4);

  // B packed base: g64 = n0/64 + wn; frag f at +f*64KB; kstep ks at +ks*1KB
  const char* gB0 = wqp + ((size_t)((n0 >> 6) + wn)) * 262144 + lane * 16;

  i32x4 acc[8][4] = {};
  i32x4 bk0[4], bk1[4], bnx[4];

  // prologue: stage A(0) into buf 0; load B(0,k0)
  GL(gA0, dA0);                    GL(gA0 + RROW, dA0 + 8192);
  GL(gA0 + 2 * RROW, dA0 + 16384); GL(gA0 + 3 * RROW, dA0 + 24576);
#pragma unroll
  for (int f = 0; f < 4; ++f) bk0[f] = *(const i32x4*)(gB0 + (size_t)f * 65536);

  for (int t = 0; t < NT - 1; ++t) {
    const int buf = t & 1;
    tile_body<true, true>(lds_c + buf * 32768 + aRowOff, colswz,
                          gA0 + (size_t)(t + 1) * 128, dA0 + (1 - buf) * 32768,
                          gB0 + (size_t)t * 2048 + 1024,       // B(t,k1)
                          gB0 + (size_t)(t + 1) * 2048,        // B(t+1,k0)
                          bk0, bk1, bnx, acc);
  }
  tile_body<false, false>(lds_c + ((NT - 1) & 1) * 32768 + aRowOff, colswz,
                          nullptr, nullptr,
                          gB0 + (size_t)(NT - 1) * 2048 + 1024, nullptr,
                          bk0, bk1, bnx, acc);

  // epilogue: C/D layout col=lane&15, row=(lane>>4)*4+reg (dtype-independent, m121/m128)
  const int orow0 = m0 + wm * 128 + (lane >> 4) * 4;
  const int ocol0 = n0 + wn * 64 + lr;
  float bv[4], swv[4];
#pragma unroll
  for (int fc = 0; fc < 4; ++fc) {
    bv[fc] = bias[ocol0 + fc * 16];
    swv[fc] = sw[ocol0 + fc * 16];
  }
#pragma unroll
  for (int fr = 0; fr < 8; ++fr) {
#pragma unroll
    for (int j = 0; j < 4; ++j) {
      const int grow = orow0 + fr * 16 + j;
      const float s = sx[grow];
      float* op = out + (size_t)grow * N_DIM + ocol0;
#pragma unroll
      for (int fc = 0; fc < 4; ++fc)
        op[fc * 16] = (float)acc[fr][fc][j] * (s * swv[fc]) + bv[fc];
    }
  }
}

extern "C" void kernel_launch(void* const* d_in, const int* in_sizes, int n_in,
                              void* d_out, int out_size, void* d_ws, size_t ws_size,
                              hipStream_t stream) {
  (void)in_sizes; (void)n_in; (void)out_size; (void)ws_size;
  const float* x = (const float*)d_in[0];       // [4,2048,4096] f32
  const float* w = (const float*)d_in[1];       // [11008,4096] f32
  const float* bias = (const float*)d_in[2];    // [1,11008] f32
  float* out = (float*)d_out;                   // [8192,11008] f32

  char* ws = (char*)d_ws;
  float* sx = (float*)ws;                                   // 32 KiB
  float* sw = (float*)(ws + 32768);                         // 44 KiB
  char* xq8 = ws + 131072;                                  // 32 MiB int8
  char* wqp = ws + 131072 + (size_t)M_DIM * K_DIM;          // 43 MiB int8 (packed)

  quant_x_kernel<<<M_DIM, 256, 0, stream>>>(x, xq8, sx);
  quant_w_kernel<<<N_DIM, 256, 0, stream>>>(w, wqp, sw);
  gemm_kernel<<<dim3((M_DIM / 256) * (N_DIM / 256)), 512, 0, stream>>>(xq8, wqp, sx, sw, bias, out);
}

// Round 11
// 451.819 us; speedup vs baseline: 8.7941x; 1.2287x over previous
//
#include <hip/hip_runtime.h>
#include <hip/hip_bf16.h>

#define M_DIM 8192
#define N_DIM 11008
#define K_DIM 4096
#define NT 32                        // K-tiles of BK=128 (int8)
#define RROW ((size_t)64 * K_DIM)    // 64 rows of int8, in bytes

typedef __attribute__((ext_vector_type(4))) int i32x4;

// ---------------- per-token activation quant: n = rint(x/s), s = max(absmax,1e-5)/7 ----------------
__global__ void quant_x_kernel(const float* __restrict__ x,
                               char* __restrict__ xq, float* __restrict__ sx) {
  const int row = blockIdx.x;      // 8192
  const int t = threadIdx.x;       // 256
  const float4* xr4 = (const float4*)(x + (size_t)row * K_DIM);
  float4 v[4];
  float amax = 0.0f;
#pragma unroll
  for (int i = 0; i < 4; ++i) {
    v[i] = xr4[t + 256 * i];
    amax = fmaxf(amax, fmaxf(fmaxf(fabsf(v[i].x), fabsf(v[i].y)),
                             fmaxf(fabsf(v[i].z), fabsf(v[i].w))));
  }
#pragma unroll
  for (int off = 32; off > 0; off >>= 1)
    amax = fmaxf(amax, __shfl_xor(amax, off, 64));
  __shared__ float red[4];
  if ((t & 63) == 0) red[t >> 6] = amax;
  __syncthreads();
  amax = fmaxf(fmaxf(red[0], red[1]), fmaxf(red[2], red[3]));
  const float s = fmaxf(amax, 1e-5f) / 7.0f;   // matches reference bitwise
  if (t == 0) sx[row] = s;
  char q[16];
#pragma unroll
  for (int i = 0; i < 4; ++i) {
    q[i * 4 + 0] = (char)(int)rintf(v[i].x / s);  // RNE, exact ints in [-7,7]
    q[i * 4 + 1] = (char)(int)rintf(v[i].y / s);
    q[i * 4 + 2] = (char)(int)rintf(v[i].z / s);
    q[i * 4 + 3] = (char)(int)rintf(v[i].w / s);
  }
  *(int4*)(xq + (size_t)row * K_DIM + t * 16) = *(int4*)q;
}

// ---------------- per-output-channel weight quant: int8 / 127 (row-major) ----------------
__global__ void quant_w_kernel(const float* __restrict__ w,
                               char* __restrict__ wq, float* __restrict__ sw) {
  const int row = blockIdx.x;      // 11008
  const int t = threadIdx.x;       // 256
  const float4* wr4 = (const float4*)(w + (size_t)row * K_DIM);
  float4 v[4];
  float amax = 0.0f;
#pragma unroll
  for (int i = 0; i < 4; ++i) {
    v[i] = wr4[t + 256 * i];
    amax = fmaxf(amax, fmaxf(fmaxf(fabsf(v[i].x), fabsf(v[i].y)),
                             fmaxf(fabsf(v[i].z), fabsf(v[i].w))));
  }
#pragma unroll
  for (int off = 32; off > 0; off >>= 1)
    amax = fmaxf(amax, __shfl_xor(amax, off, 64));
  __shared__ float red[4];
  if ((t & 63) == 0) red[t >> 6] = amax;
  __syncthreads();
  amax = fmaxf(fmaxf(red[0], red[1]), fmaxf(red[2], red[3]));
  const float s = fmaxf(amax, 1e-30f) / 127.0f;
  if (t == 0) sw[row] = s;
  char q[16];
#pragma unroll
  for (int i = 0; i < 4; ++i) {
    q[i * 4 + 0] = (char)(int)rintf(v[i].x / s);  // in [-127,127]
    q[i * 4 + 1] = (char)(int)rintf(v[i].y / s);
    q[i * 4 + 2] = (char)(int)rintf(v[i].z / s);
    q[i * 4 + 3] = (char)(int)rintf(v[i].w / s);
  }
  *(int4*)(wq + (size_t)row * K_DIM + t * 16) = *(int4*)q;
}

// ---------------- GEMM: m201-faithful 8-phase schedule, i8 ----------------
// 256x256 tile, BK=128 int8, 512 thr (8 waves 2x4), ring-2 LDS 128 KiB.
// Per tile, 4 phases of {ds_reads || stage -> s_barrier -> lgkmcnt(0)+sched_barrier
// -> setprio(1) 16xMFMA setprio(0) -> [vmcnt] -> s_barrier}.
// Stage ledger: ph1 stages A(t+1) (other buf; readers done at t-1.ph4);
// ph4 stages B(t+2) (current buf; B(t) reads done at ph3 close) + vmcnt(4)
// (12 outstanding -> 4: proves A(t)/B(t) of NEXT tile landed). Tile30: vmcnt(0).
// Swizzle (verified 0 conflicts): phys = row*128 + (col ^ ((row&7)<<4)),
// staged via inverse-swizzled global source (linear gload_lds dest).
#define GL(g, d)                                                             \
  __builtin_amdgcn_global_load_lds(                                          \
      (const __attribute__((address_space(1))) void*)(g),                    \
      (__attribute__((address_space(3))) void*)(d), 16, 0, 0)

#define MFMA_I8 __builtin_amdgcn_mfma_i32_16x16x64_i8
#define BAR() __builtin_amdgcn_s_barrier()
#define LGKM0()                                            \
  do {                                                     \
    asm volatile("s_waitcnt lgkmcnt(0)" ::: "memory");     \
    __builtin_amdgcn_sched_barrier(0);                     \
  } while (0)

#define STAGE4(g, d)                                       \
  do {                                                     \
    GL((g), (d));                                          \
    GL((g) + RROW, (d) + 8192);                            \
    GL((g) + 2 * RROW, (d) + 16384);                       \
    GL((g) + 3 * RROW, (d) + 24576);                       \
  } while (0)

template<int OFF>
__device__ __forceinline__ void mfma16(const i32x4 (&a)[4], const i32x4 (&b)[4],
                                       i32x4 (&acc)[8][4]) {
  __builtin_amdgcn_s_setprio(1);
#pragma unroll
  for (int m = 0; m < 4; ++m)
#pragma unroll
    for (int n = 0; n < 4; ++n)
      acc[OFF + m][n] = MFMA_I8(a[m], b[n], acc[OFF + m][n], 0, 0, 0);
  __builtin_amdgcn_s_setprio(0);
}

// SA: stage A(t+1); SB: stage B(t+2); VMC: 4 / 0 / -1(none)
template<bool SA, bool SB, int VMC>
__device__ __forceinline__ void ktile(const char* pa, const char* pb, int colswz,
    const char* gA1, char* dA1, const char* gB2, char* dB2, i32x4 (&acc)[8][4]) {
  const int c0 = colswz, c1 = colswz ^ 64;
  i32x4 a[4], b[4];
  // ---- ph1: A(m0-3,k0) + B(k0); stage A(t+1) ----
#pragma unroll
  for (int i = 0; i < 4; ++i) a[i] = *(const i32x4*)(pa + i * 2048 + c0);
#pragma unroll
  for (int i = 0; i < 4; ++i) b[i] = *(const i32x4*)(pb + i * 2048 + c0);
  if constexpr (SA) STAGE4(gA1, dA1);
  BAR(); LGKM0();
  mfma16<0>(a, b, acc);
  BAR();
  // ---- ph2: A(m4-7,k0); B reused from regs ----
#pragma unroll
  for (int i = 0; i < 4; ++i) a[i] = *(const i32x4*)(pa + (4 + i) * 2048 + c0);
  BAR(); LGKM0();
  mfma16<4>(a, b, acc);
  BAR();
  // ---- ph3: A(m0-3,k1) + B(k1) ----
#pragma unroll
  for (int i = 0; i < 4; ++i) a[i] = *(const i32x4*)(pa + i * 2048 + c1);
#pragma unroll
  for (int i = 0; i < 4; ++i) b[i] = *(const i32x4*)(pb + i * 2048 + c1);
  BAR(); LGKM0();
  mfma16<0>(a, b, acc);
  BAR();
  // ---- ph4: A(m4-7,k1); stage B(t+2); counted vmcnt ----
#pragma unroll
  for (int i = 0; i < 4; ++i) a[i] = *(const i32x4*)(pa + (4 + i) * 2048 + c1);
  if constexpr (SB) STAGE4(gB2, dB2);
  BAR(); LGKM0();
  mfma16<4>(a, b, acc);
  if constexpr (VMC == 4) asm volatile("s_waitcnt vmcnt(4)" ::: "memory");
  if constexpr (VMC == 0) asm volatile("s_waitcnt vmcnt(0)" ::: "memory");
  BAR();
}

__global__ __launch_bounds__(512, 2) void gemm_kernel(
    const char* __restrict__ xq, const char* __restrict__ wq,
    const float* __restrict__ sx, const float* __restrict__ sw,
    const float* __restrict__ bias, float* __restrict__ out) {
  __shared__ char lds_c[131072];  // A: [0,64K) bufs 0/1; B: [64K,128K) bufs 0/1

  const int tid = threadIdx.x;
  const int lane = tid & 63;
  const int wave = tid >> 6;
  const int wm = wave >> 2;       // 0..1
  const int wn = wave & 3;        // 0..3
  const int lr = lane & 15;

  // T1: bijective XCD swizzle (1376 = 8*172), R6 mapping
  const int bid = blockIdx.x;
  const int sw_id = (bid & 7) * 172 + (bid >> 3);
  const int bm = sw_id / 43, bn = sw_id % 43;
  const int m0 = bm * 256, n0 = bn * 256;

  // staging source (inverse swizzle, rule #21)
  const int srow = tid >> 3;
  const int srccb = ((tid & 7) << 4) ^ ((srow & 7) << 4);
  const char* gA0 = xq + (size_t)(m0 + srow) * K_DIM + srccb;
  const char* gB0 = wq + (size_t)(n0 + srow) * K_DIM + srccb;
  char* dA0 = lds_c + wave * 1024;            // wave-uniform; HW adds lane*16
  char* dB0 = lds_c + 65536 + wave * 1024;

  // read-side bases (swizzled)
  const int aRowOff = (wm * 128 + lr) * 128;
  const int bRowOff = (wn * 64 + lr) * 128;
  const int colswz = ((lane >> 4) << 4) ^ ((lr & 7) << 4);

  i32x4 acc[8][4] = {};

  // prologue: stage tiles 0 (buf0) and 1 (buf1); wait tile-0's 8, keep tile-1's in flight
  STAGE4(gA0, dA0);              STAGE4(gB0, dB0);
  STAGE4(gA0 + 128, dA0 + 32768); STAGE4(gB0 + 128, dB0 + 32768);
  asm volatile("s_waitcnt vmcnt(8)" ::: "memory");
  BAR();

  // tile 0: no A-stage (A(1) prologue), stage B(2), vmcnt(4)
  ktile<false, true, 4>(lds_c + aRowOff, lds_c + 65536 + bRowOff, colswz,
                        nullptr, nullptr, gB0 + 2 * 128, dB0, acc);
  // tiles 1..29: stage A(t+1) -> other buf, B(t+2) -> current buf, vmcnt(4)
  for (int t = 1; t <= 29; ++t) {
    const int buf = t & 1;
    ktile<true, true, 4>(lds_c + buf * 32768 + aRowOff,
                         lds_c + 65536 + buf * 32768 + bRowOff, colswz,
                         gA0 + (size_t)(t + 1) * 128, dA0 + (1 - buf) * 32768,
                         gB0 + (size_t)(t + 2) * 128, dB0 + buf * 32768, acc);
  }
  // tile 30: stage A(31), no B, vmcnt(0) (full drain so tile 31's reads are safe)
  ktile<true, false, 0>(lds_c + aRowOff, lds_c + 65536 + bRowOff, colswz,
                        gA0 + (size_t)31 * 128, dA0 + 32768, nullptr, nullptr, acc);
  // tile 31: nothing staged, no vmcnt
  ktile<false, false, -1>(lds_c + 32768 + aRowOff, lds_c + 65536 + 32768 + bRowOff,
                          colswz, nullptr, nullptr, nullptr, nullptr, acc);

  // epilogue: C/D layout col=lane&15, row=(lane>>4)*4+reg (dtype-independent, m121/m128)
  const int orow0 = m0 + wm * 128 + (lane >> 4) * 4;
  const int ocol0 = n0 + wn * 64 + lr;
  float bv[4], swv[4];
#pragma unroll
  for (int fc = 0; fc < 4; ++fc) {
    bv[fc] = bias[ocol0 + fc * 16];
    swv[fc] = sw[ocol0 + fc * 16];
  }
#pragma unroll
  for (int fr = 0; fr < 8; ++fr) {
#pragma unroll
    for (int j = 0; j < 4; ++j) {
      const int grow = orow0 + fr * 16 + j;
      const float s = sx[grow];
      float* op = out + (size_t)grow * N_DIM + ocol0;
#pragma unroll
      for (int fc = 0; fc < 4; ++fc)
        op[fc * 16] = (float)acc[fr][fc][j] * (s * swv[fc]) + bv[fc];
    }
  }
}

extern "C" void kernel_launch(void* const* d_in, const int* in_sizes, int n_in,
                              void* d_out, int out_size, void* d_ws, size_t ws_size,
                              hipStream_t stream) {
  (void)in_sizes; (void)n_in; (void)out_size; (void)ws_size;
  const float* x = (const float*)d_in[0];       // [4,2048,4096] f32
  const float* w = (const float*)d_in[1];       // [11008,4096] f32
  const float* bias = (const float*)d_in[2];    // [1,11008] f32
  float* out = (float*)d_out;                   // [8192,11008] f32

  char* ws = (char*)d_ws;
  float* sx = (float*)ws;                                   // 32 KiB
  float* sw = (float*)(ws + 32768);                         // 44 KiB
  char* xq8 = ws + 131072;                                  // 32 MiB int8
  char* wq8 = ws + 131072 + (size_t)M_DIM * K_DIM;          // 43 MiB int8

  quant_x_kernel<<<M_DIM, 256, 0, stream>>>(x, xq8, sx);
  quant_w_kernel<<<N_DIM, 256, 0, stream>>>(w, wq8, sw);
  gemm_kernel<<<dim3((M_DIM / 256) * (N_DIM / 256)), 512, 0, stream>>>(xq8, wq8, sx, sw, bias, out);
}